// Round 15
// baseline (127.593 us; speedup 1.0000x reference)
//
#include <hip/hip_runtime.h>
#include <hip/hip_bf16.h>
#include <stdint.h>

#define P    300
#define HID  128
#define NG   1000
#define QR   80          // quarter rows: 79 valid (75 owned + 2+2 halo) + 1 pad

typedef __attribute__((ext_vector_type(8))) short bf16x8;
typedef __attribute__((ext_vector_type(4))) float f32x4;

// Swizzled bf16 W^T. Slot fkey holds weights for column perm(fkey):
// W2 (pass0): perm(fkey) = u*32 + 2*(fkey&15) + ((fkey>>4)&1), u=fkey>>5
//   -> computed feature IS the physical store position, so h2 is natural
//      and W3 (pass1) is natural. chunk(fkey,kc) at fkey*16+(kc^(fkey&15)).
__device__ short g_wsw[2 * HID * HID];
__device__ float g_pool[NG * 4 * HID];   // [graph][quarter][feature] partials

__device__ __forceinline__ short f2bf(float f) {
    union { float f; uint32_t u; } v; v.f = f;
    uint32_t r = v.u + 0x7fffu + ((v.u >> 16) & 1u);   // RNE
    return (short)(r >> 16);
}
__device__ __forceinline__ float bf2f(short s) {
    union { uint32_t u; float f; } v; v.u = ((uint32_t)(uint16_t)s) << 16;
    return v.f;
}
__device__ __forceinline__ uint32_t pkbf2(float a, float b) {   // low=a, high=b
    union { __hip_bfloat162 h; uint32_t u; } cv;
    cv.h = __float22bfloat162_rn(float2{a, b});
    return cv.u;
}
__device__ __forceinline__ float unpk(int v, int ft) {
    return bf2f((short)(ft ? (((uint32_t)v) >> 16) : (v & 0xffff)));
}

__global__ __launch_bounds__(256) void k_prep(const float* __restrict__ W2,
                                              const float* __restrict__ W3) {
    int b = blockIdx.x;                       // 16 blocks
    const bool perm = (b < 8);
    const float* W = perm ? W2 : W3;
    short* dst = g_wsw + (perm ? 0 : HID * HID);
    int t    = (b & 7) * 256 + threadIdx.x;   // 0..2047 chunks
    int fkey = t >> 4;
    int kc   = t & 15;
    int fsrc;
    if (perm) {
        int u = fkey >> 5, ft = (fkey >> 4) & 1, l = fkey & 15;
        fsrc = u * 32 + 2 * l + ft;
    } else fsrc = fkey;
    bf16x8 o;
    #pragma unroll
    for (int j = 0; j < 8; ++j)
        o[j] = f2bf(W[(kc * 8 + j) * HID + fsrc]);
    *(bf16x8*)&dst[(fkey * 16 + (kc ^ (fkey & 15))) * 8] = o;
}

// ring-average + bias + relu over 4 consecutive node-rows (f32 in regs)
__device__ __forceinline__ void avg_epi(const f32x4 &G, float vp0, float vn3,
                                        float b, float* o) {
    o[0] = (vp0  + G[0] + G[1]) * (1.0f / 3.0f) + b;
    o[1] = (G[0] + G[1] + G[2]) * (1.0f / 3.0f) + b;
    o[2] = (G[1] + G[2] + G[3]) * (1.0f / 3.0f) + b;
    o[3] = (G[2] + G[3] + vn3 ) * (1.0f / 3.0f) + b;
    #pragma unroll
    for (int i = 0; i < 4; ++i) o[i] = o[i] > 0.f ? o[i] : 0.f;
}

// One GCN layer over a QUARTER-ring (path, 5 tiles, 80 rows); 4 waves,
// 2 ft-tiles/wave (lowest LDS redundancy: 4 waves cover 128 features).
// Rationale (r14 post-mortem): 512-thread blocks cap at 2 workgroups/CU
// regardless of LDS headroom; 256-thread blocks are the proven shape for
// multi-residency. Quarter blocks (21 KB, ~85 VGPR target) allow 5-6
// blocks/CU = 20-24 waves/CU with r4-level LDS traffic. Halo rows
// duplicate-computed (+6.7% MFMA); no ring wrap (lives in x-staging mod).
// ROLLING 2-BARRIER path schedule, race-proof:
//   reads {0,1,2}; BAR1; reads {3,4} interleaved w/ stores {0,1}; BAR2;
//   stores {2,3,4}. Stores{0,1} vs reads{3,4}: disjoint; all reads of a
//   tile precede its store via the preceding barrier.
// Row masks [LO,HI] compile-time: pass0 [1,77], pass1 [2,76] (=owned).
// Valid row r needs G rows r-1..r+1 fresh: pass0 needs h1 0..78 (layer-1
// computes 0..78, row 79 zero); pass1 needs h2 1..77 (= pass0 stores).
template<int POOL, int LO, int HI>
__device__ __forceinline__ void run_pass(short* __restrict__ buf,
                                         const short* __restrict__ wbase,
                                         const float* __restrict__ bias,
                                         float* __restrict__ pool, int tid) {
    const int lane = tid & 63, wv = tid >> 6, q = lane >> 4, lm = lane & 15;
    const int ftg0 = wv * 2;
    bf16x8 wf[2][4];
    #pragma unroll
    for (int ft = 0; ft < 2; ++ft) {
        int fkey = (ftg0 + ft) * 16 + lm;
        #pragma unroll
        for (int kk = 0; kk < 4; ++kk)
            wf[ft][kk] = *(const bf16x8*)&wbase[(fkey * 16 + ((4 * kk + q) ^ lm)) * 8];
    }
    float biaf[2];
    #pragma unroll
    for (int ft = 0; ft < 2; ++ft)
        biaf[ft] = POOL ? bias[(ftg0 + ft) * 16 + lm] : bias[wv * 32 + 2 * lm + ft];
    const int fpair = wv * 32 + 2 * lm;       // even physical feature (pass0)
    const int kcs = fpair >> 3, offs = fpair & 7;
    const int sA = (q == 0) ? (48 + lm) : (lane - 16);  // r15 carry / row above
    const int sB = (lane + 16) & 63;                    // row below (q<3)

    float psum[2] = {0.f, 0.f};
    float c15[2] = {0.f, 0.f};

    auto mfma_tile = [&](int t, f32x4 (&G)[2]) {
        const short* tb = buf + t * 2048;
        G[0] = f32x4{0.f, 0.f, 0.f, 0.f};
        G[1] = f32x4{0.f, 0.f, 0.f, 0.f};
        #pragma unroll
        for (int kk = 0; kk < 4; ++kk) {
            bf16x8 af = *(const bf16x8*)&tb[(lm * 16 + ((4 * kk + q) ^ lm)) * 8];
            G[0] = __builtin_amdgcn_mfma_f32_16x16x32_bf16(af, wf[0][kk], G[0], 0, 0, 0);
            G[1] = __builtin_amdgcn_mfma_f32_16x16x32_bf16(af, wf[1][kk], G[1], 0, 0, 0);
        }
    };
    auto store_rows = [&](int T, float (&o)[2][4]) {
        #pragma unroll
        for (int i = 0; i < 4; ++i) {
            int r = T * 16 + q * 4 + i;
            if (r >= LO && r <= HI)
                *(uint32_t*)&buf[(r * 16 + (kcs ^ (r & 15))) * 8 + offs] =
                    pkbf2(o[0][i], o[1][i]);
        }
    };
    auto accum = [&](int T, float (&o)[2][4]) {
        #pragma unroll
        for (int i = 0; i < 4; ++i) {
            int r = T * 16 + q * 4 + i;
            if (r >= LO && r <= HI) { psum[0] += o[0][i]; psum[1] += o[1][i]; }
        }
    };
    // packed epilogue (r4-proven): E centers; N = next tile (r0 only used
    // at q==3; garbage OK when those rows are masked).
    auto epi = [&](const f32x4 (&E)[2], const f32x4 (&N)[2], float (&o)[2][4]) {
        uint32_t uE3 = pkbf2(E[0][3], E[1][3]);
        uint32_t uE0 = pkbf2(E[0][0], E[1][0]);
        uint32_t uN0 = pkbf2(N[0][0], N[1][0]);
        int vA = __shfl((int)uE3, sA, 64);
        int vB = __shfl((int)uE0, sB, 64);
        int vC = __shfl((int)uN0, lm, 64);
        #pragma unroll
        for (int ft = 0; ft < 2; ++ft) {
            float bpA = unpk(vA, ft);
            float vp0 = (q == 0) ? c15[ft] : bpA;
            float vn3 = (q == 3) ? unpk(vC, ft) : unpk(vB, ft);
            avg_epi(E[ft], vp0, vn3, biaf[ft], o[ft]);
            c15[ft] = bpA;        // this tile's r15 -> next tile's vp0(q==0)
        }
    };

    f32x4 Ga[2], Gb[2], Gc[2], Gd[2], Ge[2];

    mfma_tile(0, Ga);
    mfma_tile(1, Gb);
    mfma_tile(2, Gc);
    if (!POOL) __syncthreads();               // BAR1: reads {0,1,2} done

    mfma_tile(3, Gd);
    {   // tile 0 (row0's vp0 = c15 garbage -> row0 < LO, masked)
        float o[2][4];
        epi(Ga, Gb, o);
        if (POOL) accum(0, o); else store_rows(0, o);
    }
    mfma_tile(4, Ge);
    {   // tile 1
        float o[2][4];
        epi(Gb, Gc, o);
        if (POOL) accum(1, o); else store_rows(1, o);
    }
    if (!POOL) __syncthreads();               // BAR2: reads {3,4} done

    {
        float o[2][4];
        epi(Gc, Gd, o);
        if (POOL) accum(2, o); else store_rows(2, o);
    }
    {
        float o[2][4];
        epi(Gd, Ge, o);
        if (POOL) accum(3, o); else store_rows(3, o);
    }
    {   // tile 4: N unused for valid rows (q==3 rows 76..79: 78,79 masked;
        // o[3]=row79 is the only vn3 consumer -> masked)
        float o[2][4];
        epi(Ge, Ge, o);
        if (POOL) accum(4, o); else store_rows(4, o);
    }

    if (POOL) {
        #pragma unroll
        for (int ft = 0; ft < 2; ++ft) {
            psum[ft] += __shfl_xor(psum[ft], 16, 64);
            psum[ft] += __shfl_xor(psum[ft], 32, 64);
        }
        if (q == 0) {
            pool[ftg0 * 16 + lm]        = psum[0];
            pool[(ftg0 + 1) * 16 + lm]  = psum[1];
        }
    }
}

// One block (256 thr, 4 waves) per QUARTER-graph. LDS ~21.2 KB; VGPR
// target <= ~85 -> 5-6 blocks/CU (VGPR pool 512/SIMD-lane, m69) =
// 20-24 waves/CU. (256,2) caps arch VGPR at 128 (r0/r5-verified).
__global__ __launch_bounds__(256, 2) void k_graph(
        const float* __restrict__ x,
        const float* __restrict__ W1,  const float* __restrict__ b1,
        const float* __restrict__ b2v, const float* __restrict__ b3v) {
    __shared__ __align__(16) short buf[QR * HID];   // 20480 B, chunk-swizzled
    __shared__ __align__(16) float xs[164];         // 656 B
    const int bid = blockIdx.x, g = bid >> 2, qt = bid & 3;
    const int tid = threadIdx.x;
    const int start = qt * 75;

    // stage x for nodes (start-3 .. start+77) mod 300: xs[2t] <-> start-3+t
    if (tid < 81) {
        int gn = start - 3 + tid;
        gn += (gn < 0) ? P : 0;
        gn -= (gn >= P) ? P : 0;
        *(float2*)&xs[2 * tid] = *(const float2*)&x[g * 600 + gn * 2];
    }
    __syncthreads();

    // ---- layer 1: h1[lr] = relu(avg3(x)@W1+b1), lr 0..78; row 79 zero ----
    // h1 row lr <-> node start-2+lr; avg3 = xs rows lr, lr+1, lr+2.
    {
        const int kc1 = tid & 15;
        const int n0  = tid >> 4;            // 0..15
        float w1x[8], w1y[8], b1v[8];
        #pragma unroll
        for (int j = 0; j < 8; ++j) {
            w1x[j] = W1[kc1 * 8 + j];
            w1y[j] = W1[HID + kc1 * 8 + j];
            b1v[j] = b1[kc1 * 8 + j];
        }
        #pragma unroll
        for (int it = 0; it < 5; ++it) {
            int row = it * 16 + n0;          // 0..79
            uint32_t w[4] = {0u, 0u, 0u, 0u};
            if (row < 79) {
                float2 xp = *(const float2*)&xs[2 * row];
                float2 xc = *(const float2*)&xs[2 * row + 2];
                float2 xn = *(const float2*)&xs[2 * row + 4];
                float ax = (xp.x + xc.x + xn.x) * (1.f / 3.f);
                float ay = (xp.y + xc.y + xn.y) * (1.f / 3.f);
                #pragma unroll
                for (int jj = 0; jj < 4; ++jj) {
                    float va = ax * w1x[2*jj]   + ay * w1y[2*jj]   + b1v[2*jj];
                    float vb = ax * w1x[2*jj+1] + ay * w1y[2*jj+1] + b1v[2*jj+1];
                    va = va > 0.f ? va : 0.f;
                    vb = vb > 0.f ? vb : 0.f;
                    w[jj] = pkbf2(va, vb);
                }
            }
            *(uint4*)&buf[(row * 16 + (kc1 ^ (row & 15))) * 8] =
                uint4{w[0], w[1], w[2], w[3]};
        }
    }
    __syncthreads();

    run_pass<0, 1, 77>(buf, g_wsw,             b2v, nullptr, tid);
    __syncthreads();
    run_pass<1, 2, 76>(buf, g_wsw + HID * HID, b3v,
                       &g_pool[(g * 4 + qt) * HID], tid);
}

// pool-merge (4 quarters) + FC head; kernel boundary = g_pool coherence.
__global__ __launch_bounds__(128) void k_fc(
        const float* __restrict__ fw1, const float* __restrict__ fb1,
        const float* __restrict__ fw2, const float* __restrict__ fb2,
        float* __restrict__ out) {
    __shared__ float pl[128], s1[128];
    const int g = blockIdx.x, f = threadIdx.x;
    pl[f] = g_pool[g * 512 + f]       + g_pool[g * 512 + 128 + f]
          + g_pool[g * 512 + 256 + f] + g_pool[g * 512 + 384 + f];
    __syncthreads();
    float p = 0.f;
    const float* c = fw1 + f;
    #pragma unroll 8
    for (int k = 0; k < 128; ++k) p += pl[k] * c[k * 128];
    float o1 = fb1[f] + p * (1.0f / 300.0f);
    s1[f] = o1 > 0.f ? o1 : 0.f;
    __syncthreads();
    int o = f >> 6, ln = f & 63;
    float v = s1[ln] * fw2[ln * 2 + o] + s1[ln + 64] * fw2[(ln + 64) * 2 + o];
    #pragma unroll
    for (int off = 1; off <= 32; off <<= 1)
        v += __shfl_xor(v, off, 64);
    if (ln == 0) out[g * 2 + o] = v + fb2[o];
}

extern "C" void kernel_launch(void* const* d_in, const int* in_sizes, int n_in,
                              void* d_out, int out_size, void* d_ws, size_t ws_size,
                              hipStream_t stream) {
    const float* x   = (const float*)d_in[0];
    const float* W1  = (const float*)d_in[3];
    const float* b1  = (const float*)d_in[4];
    const float* W2  = (const float*)d_in[5];
    const float* b2  = (const float*)d_in[6];
    const float* W3  = (const float*)d_in[7];
    const float* b3  = (const float*)d_in[8];
    const float* fw1 = (const float*)d_in[9];
    const float* fb1 = (const float*)d_in[10];
    const float* fw2 = (const float*)d_in[11];
    const float* fb2 = (const float*)d_in[12];
    float* out = (float*)d_out;

    k_prep <<<dim3(16),     dim3(256), 0, stream>>>(W2, W3);
    k_graph<<<dim3(4 * NG), dim3(256), 0, stream>>>(x, W1, b1, b2, b3);
    k_fc   <<<dim3(NG),     dim3(128), 0, stream>>>(fw1, fb1, fw2, fb2, out);
}